// Round 2
// baseline (837.680 us; speedup 1.0000x reference)
//
#include <hip/hip_runtime.h>
#include <hip/hip_bf16.h>

#define TOKENS (16*1024)
#define HD 512
#define MM 2048

typedef short s16x8 __attribute__((ext_vector_type(8)));
typedef float f32x4 __attribute__((ext_vector_type(4)));

__device__ __forceinline__ __hip_bfloat16 f2bf(float v){ return __float2bfloat16(v); }
__device__ __forceinline__ float bf2f(__hip_bfloat16 v){ return __bfloat162float(v); }

// block-wide sum of two floats across 256 threads (4 waves of 64)
__device__ __forceinline__ void block_reduce2(float& a, float& b, float* sred){
  const int tid = threadIdx.x;
  #pragma unroll
  for (int o = 32; o > 0; o >>= 1){ a += __shfl_down(a, o); b += __shfl_down(b, o); }
  if ((tid & 63) == 0){ sred[tid >> 6] = a; sred[4 + (tid >> 6)] = b; }
  __syncthreads();
  float ra = sred[0] + sred[1] + sred[2] + sred[3];
  float rb = sred[4] + sred[5] + sred[6] + sred[7];
  __syncthreads();   // sred reusable after this
  a = ra; b = rb;
}

__global__ __launch_bounds__(256)
void fused_stage_a(const float* __restrict__ x,
                   const float* __restrict__ ctx,
                   const float* __restrict__ ln1w, const float* __restrict__ ln1b,
                   const float* __restrict__ w_qkv, const float* __restrict__ b_qkv,
                   const float* __restrict__ w_fc_s, const float* __restrict__ b_fc_s,
                   const float* __restrict__ ln2w, const float* __restrict__ ln2b,
                   const float* __restrict__ w_q, const float* __restrict__ b_q,
                   const float* __restrict__ w_kv, const float* __restrict__ b_kv,
                   const float* __restrict__ w_fc_c, const float* __restrict__ b_fc_c,
                   const float* __restrict__ ln3w, const float* __restrict__ ln3b,
                   float* __restrict__ xca_out,            // = d_out (x_ca; residual added by gemm2)
                   __hip_bfloat16* __restrict__ y_out)     // = ws: LN3(x_ca) bf16, GEMM1 input
{
  __shared__ float s_xin[512];   // LN1(x); later raw context row
  __shared__ float s_qkv[1536];  // qkv; later kv (1024)
  __shared__ float s_att[512];   // attn output [c][k]
  __shared__ float s_h[512];     // LN2 output
  __shared__ float s_q2[512];    // cross-attn q
  __shared__ float s_w[512];     // per-(j,c): v_c / den_c
  __shared__ float s_red[8];

  const int tid = threadIdx.x;
  const size_t base = (size_t)blockIdx.x * HD;

  // ---------------- LN1 ----------------
  float xv0 = x[base + tid], xv1 = x[base + 256 + tid];
  float sm = xv0 + xv1, sq = xv0*xv0 + xv1*xv1;
  block_reduce2(sm, sq, s_red);
  float mu = sm * (1.f/512.f);
  float rs = rsqrtf(sq * (1.f/512.f) - mu*mu + 1e-6f);
  s_xin[tid]       = (xv0 - mu)*rs*ln1w[tid]       + ln1b[tid];
  s_xin[tid + 256] = (xv1 - mu)*rs*ln1w[tid + 256] + ln1b[tid + 256];
  __syncthreads();

  // ---------------- qkv projection: [c][d] d in 0..191 ----------------
  for (int o = tid; o < 1536; o += 256){
    int c = o / 192, d = o - c*192;
    const float* wp = w_qkv + (size_t)(c*64)*192 + d;
    const float* xp = s_xin + c*64;
    float acc = b_qkv[o];
    #pragma unroll 8
    for (int k = 0; k < 64; k++) acc += xp[k] * wp[(size_t)k*192];
    s_qkv[o] = acc;
  }
  __syncthreads();

  // ---------------- criss-cross attention #1 ----------------
  {
    const int j = tid >> 2, s4 = tid & 3;
    float kk[8], qs[8];
    #pragma unroll
    for (int m = 0; m < 8; m++) kk[m] = s_qkv[m*192 + 64 + j];
    #pragma unroll
    for (int c = 0; c < 8; c++) qs[c] = s_qkv[c*192 + j] * 0.125f;
    #pragma unroll
    for (int cc2 = 0; cc2 < 2; cc2++){
      int c = s4*2 + cc2;
      float den = 0.f;
      #pragma unroll
      for (int m = 0; m < 8; m++) den += __expf(qs[c]*kk[m]);
      s_w[j*8 + c] = s_qkv[c*192 + 128 + j] / den;
    }
    __syncthreads();
    #pragma unroll
    for (int mm = 0; mm < 2; mm++){
      int m = s4*2 + mm;
      float cv = 0.f;
      #pragma unroll
      for (int c = 0; c < 8; c++) cv += s_w[j*8 + c] * __expf(qs[c]*kk[m]);
      s_att[m*64 + j] = cv;   // sa3[c=m][k=j]
    }
  }
  __syncthreads();

  // ---------------- fc_s + residual + LN2 ----------------
  float v2[2];
  #pragma unroll
  for (int l = 0; l < 2; l++){
    int i = tid + l*256, c = i >> 6, d = i & 63;
    const float* ap = s_att + c*64;
    float acc = b_fc_s[d];
    #pragma unroll 8
    for (int k = 0; k < 64; k++) acc += ap[k] * w_fc_s[k*64 + d];
    v2[l] = s_xin[i] + acc;
  }
  sm = v2[0] + v2[1]; sq = v2[0]*v2[0] + v2[1]*v2[1];
  block_reduce2(sm, sq, s_red);
  mu = sm * (1.f/512.f);
  rs = rsqrtf(sq * (1.f/512.f) - mu*mu + 1e-6f);
  s_h[tid]       = (v2[0] - mu)*rs*ln2w[tid]       + ln2b[tid];
  s_h[tid + 256] = (v2[1] - mu)*rs*ln2w[tid + 256] + ln2b[tid + 256];
  __syncthreads();

  // ---------------- cross q ; load raw context ----------------
  #pragma unroll
  for (int l = 0; l < 2; l++){
    int i = tid + l*256, c = i >> 6, d = i & 63;
    const float* hp = s_h + c*64;
    float acc = b_q[i];
    #pragma unroll 8
    for (int k = 0; k < 64; k++) acc += hp[k] * w_q[(size_t)(c*64 + k)*64 + d];
    s_q2[i] = acc;
  }
  s_xin[tid]       = ctx[base + tid];        // overwrite (LN1 out no longer needed)
  s_xin[tid + 256] = ctx[base + 256 + tid];
  __syncthreads();

  // ---------------- kv projection (context, no LN) ----------------
  for (int o = tid; o < 1024; o += 256){
    int c = o >> 7, d = o & 127;
    const float* cp = s_xin + c*64;
    float acc = b_kv[o];
    #pragma unroll 8
    for (int k = 0; k < 64; k++) acc += cp[k] * w_kv[(size_t)(c*64 + k)*128 + d];
    s_qkv[o] = acc;
  }
  __syncthreads();

  // ---------------- criss-cross attention #2 ----------------
  {
    const int j = tid >> 2, s4 = tid & 3;
    float kk[8], qs[8];
    #pragma unroll
    for (int m = 0; m < 8; m++) kk[m] = s_qkv[m*128 + j];
    #pragma unroll
    for (int c = 0; c < 8; c++) qs[c] = s_q2[c*64 + j] * 0.125f;
    #pragma unroll
    for (int cc2 = 0; cc2 < 2; cc2++){
      int c = s4*2 + cc2;
      float den = 0.f;
      #pragma unroll
      for (int m = 0; m < 8; m++) den += __expf(qs[c]*kk[m]);
      s_w[j*8 + c] = s_qkv[c*128 + 64 + j] / den;
    }
    __syncthreads();
    #pragma unroll
    for (int mm = 0; mm < 2; mm++){
      int m = s4*2 + mm;
      float cv = 0.f;
      #pragma unroll
      for (int c = 0; c < 8; c++) cv += s_w[j*8 + c] * __expf(qs[c]*kk[m]);
      s_att[m*64 + j] = cv;
    }
  }
  __syncthreads();

  // ---------------- fc_c -> x_ca ; LN3 -> Y(bf16) ----------------
  float xc[2];
  #pragma unroll
  for (int l = 0; l < 2; l++){
    int i = tid + l*256, c = i >> 6, d = i & 63;
    const float* ap = s_att + c*64;
    float acc = b_fc_c[d];
    #pragma unroll 8
    for (int k = 0; k < 64; k++) acc += ap[k] * w_fc_c[k*64 + d];
    xc[l] = acc;
    xca_out[base + i] = acc;
  }
  sm = xc[0] + xc[1]; sq = xc[0]*xc[0] + xc[1]*xc[1];
  block_reduce2(sm, sq, s_red);
  mu = sm * (1.f/512.f);
  rs = rsqrtf(sq * (1.f/512.f) - mu*mu + 1e-6f);
  #pragma unroll
  for (int l = 0; l < 2; l++){
    int i = tid + l*256;
    y_out[base + i] = f2bf((xc[l] - mu)*rs*ln3w[i] + ln3b[i]);
  }
}

// ---------------- MFMA GEMM: D = A(MxK,bf16) * B(KxN,f32->bf16) + bias ----------------
// EPI 1: Dst = bf16 mid, gelu epilogue.  EPI 2: Dst = f32 out, += residual (x_ca in DstF).
__device__ __forceinline__ float gelu_exact(float v){
  return 0.5f * v * (1.f + erff(v * 0.70710678118f));
}

template<int EPI>
__global__ __launch_bounds__(256)
void gemm_mfma(const __hip_bfloat16* __restrict__ A, const float* __restrict__ B,
               const float* __restrict__ bias,
               __hip_bfloat16* __restrict__ DstB, float* __restrict__ DstF,
               int M_, int N_, int K_)
{
  __shared__ __align__(16) unsigned short As[128*32];  // A tile, row-major [128][32]
  __shared__ __align__(16) unsigned short Bs[128*32];  // B tile, transposed [n][k] = [128][32]

  const int tid  = threadIdx.x;
  const int row0 = blockIdx.x * 128, col0 = blockIdx.y * 128;
  const int lane = tid & 63, wave = tid >> 6;
  const int wr = (wave >> 1) * 64, wc = (wave & 1) * 64;
  const int lr = lane & 15, lk = (lane >> 4) * 8;

  f32x4 acc[4][4];
  #pragma unroll
  for (int i = 0; i < 4; i++)
    #pragma unroll
    for (int j = 0; j < 4; j++)
      #pragma unroll
      for (int r = 0; r < 4; r++) acc[i][j][r] = 0.f;

  for (int k0 = 0; k0 < K_; k0 += 32){
    // A: bf16 source, 16B vector copies
    #pragma unroll
    for (int l = 0; l < 2; l++){
      int off = (l*256 + tid) * 8;
      int r = off >> 5, kc = off & 31;
      uint4 v = *(const uint4*)((const void*)(A + (size_t)(row0 + r)*K_ + k0 + kc));
      *(uint4*)((void*)(As + r*32 + kc)) = v;
    }
    // B: f32 source -> convert to bf16, transposed store [n][k]
    #pragma unroll
    for (int l = 0; l < 2; l++){
      int off = (l*256 + tid) * 8;
      int kr = off >> 7, nc = off & 127;
      const float* bp = B + (size_t)(k0 + kr)*N_ + col0 + nc;
      float4 v0 = *(const float4*)((const void*)bp);
      float4 v1 = *(const float4*)((const void*)(bp + 4));
      __hip_bfloat16 bv[8] = { f2bf(v0.x), f2bf(v0.y), f2bf(v0.z), f2bf(v0.w),
                               f2bf(v1.x), f2bf(v1.y), f2bf(v1.z), f2bf(v1.w) };
      #pragma unroll
      for (int e = 0; e < 8; e++)
        Bs[(nc + e)*32 + kr] = *(const unsigned short*)&bv[e];
    }
    __syncthreads();

    s16x8 af[4], bfr[4];
    #pragma unroll
    for (int i = 0; i < 4; i++) af[i]  = *(const s16x8*)((const void*)(As + (wr + i*16 + lr)*32 + lk));
    #pragma unroll
    for (int j = 0; j < 4; j++) bfr[j] = *(const s16x8*)((const void*)(Bs + (wc + j*16 + lr)*32 + lk));
    #pragma unroll
    for (int i = 0; i < 4; i++)
      #pragma unroll
      for (int j = 0; j < 4; j++)
        acc[i][j] = __builtin_amdgcn_mfma_f32_16x16x32_bf16(af[i], bfr[j], acc[i][j], 0, 0, 0);
    __syncthreads();
  }

  // epilogue: C/D layout col = lane&15, row = (lane>>4)*4 + r  [m89-verified]
  #pragma unroll
  for (int i = 0; i < 4; i++)
    #pragma unroll
    for (int j = 0; j < 4; j++){
      int col = col0 + wc + j*16 + lr;
      float bc = bias[col];
      #pragma unroll
      for (int r = 0; r < 4; r++){
        int row = row0 + wr + i*16 + (lane >> 4)*4 + r;
        size_t idx = (size_t)row * N_ + col;
        float v = acc[i][j][r] + bc;
        if (EPI == 1) DstB[idx] = f2bf(gelu_exact(v));
        else          DstF[idx] += v;   // DstF holds x_ca
      }
    }
}

extern "C" void kernel_launch(void* const* d_in, const int* in_sizes, int n_in,
                              void* d_out, int out_size, void* d_ws, size_t ws_size,
                              hipStream_t stream)
{
  const float* x      = (const float*)d_in[0];
  const float* ctx    = (const float*)d_in[1];
  const float* ln1w   = (const float*)d_in[2];
  const float* ln1b   = (const float*)d_in[3];
  const float* w_qkv  = (const float*)d_in[4];
  const float* b_qkv  = (const float*)d_in[5];
  const float* w_fc_s = (const float*)d_in[6];
  const float* b_fc_s = (const float*)d_in[7];
  const float* ln2w   = (const float*)d_in[8];
  const float* ln2b   = (const float*)d_in[9];
  const float* w_q    = (const float*)d_in[10];
  const float* b_q    = (const float*)d_in[11];
  const float* w_kv   = (const float*)d_in[12];
  const float* b_kv   = (const float*)d_in[13];
  const float* w_fc_c = (const float*)d_in[14];
  const float* b_fc_c = (const float*)d_in[15];
  const float* ln3w   = (const float*)d_in[16];
  const float* ln3b   = (const float*)d_in[17];
  const float* w1     = (const float*)d_in[18];
  const float* b1     = (const float*)d_in[19];
  const float* w2     = (const float*)d_in[20];
  const float* b2     = (const float*)d_in[21];

  float* out = (float*)d_out;
  __hip_bfloat16* Y   = (__hip_bfloat16*)d_ws;                                   // 16384x512 bf16 (16MB)
  __hip_bfloat16* mid = (__hip_bfloat16*)((char*)d_ws + (size_t)TOKENS*HD*2);    // 16384x2048 bf16 (64MB)

  fused_stage_a<<<TOKENS, 256, 0, stream>>>(x, ctx, ln1w, ln1b, w_qkv, b_qkv,
                                            w_fc_s, b_fc_s, ln2w, ln2b, w_q, b_q,
                                            w_kv, b_kv, w_fc_c, b_fc_c, ln3w, ln3b,
                                            out, Y);

  gemm_mfma<1><<<dim3(TOKENS/128, MM/128), 256, 0, stream>>>(Y,   w1, b1, mid, nullptr, TOKENS, MM, HD);
  gemm_mfma<2><<<dim3(TOKENS/128, HD/128), 256, 0, stream>>>(mid, w2, b2, nullptr, out, TOKENS, HD, MM);
}

// Round 3
// 431.701 us; speedup vs baseline: 1.9404x; 1.9404x over previous
//
#include <hip/hip_runtime.h>
#include <hip/hip_bf16.h>

#define TOKENS (16*1024)
#define HD 512
#define MM 2048
#define TB 16   // tokens per stage_a block

typedef short s16x8 __attribute__((ext_vector_type(8)));
typedef float f32x4 __attribute__((ext_vector_type(4)));

__device__ __forceinline__ __hip_bfloat16 f2bf(float v){ return __float2bfloat16(v); }
__device__ __forceinline__ float bf2f(__hip_bfloat16 v){ return __bfloat162float(v); }
__device__ __forceinline__ unsigned short f2bfu(float v){
  __hip_bfloat16 b = __float2bfloat16(v);
  unsigned short u; __builtin_memcpy(&u, &b, 2); return u;
}
__device__ __forceinline__ float bfu2f(unsigned short u){
  unsigned int x = ((unsigned int)u) << 16; float f; __builtin_memcpy(&f, &x, 4); return f;
}
__device__ __forceinline__ uint4 pack8(const float* v){
  unsigned short s[8];
  #pragma unroll
  for (int e = 0; e < 8; e++) s[e] = f2bfu(v[e]);
  uint4 u; __builtin_memcpy(&u, s, 16); return u;
}
__device__ __forceinline__ void unpack8(uint4 u, float* v){
  const unsigned short* s = (const unsigned short*)&u;
  #pragma unroll
  for (int e = 0; e < 8; e++) v[e] = bfu2f(s[e]);
}

#define SWZ(t) (((t) & 7) << 4)

// ---- MFMA projection: out[t][c*ND+d] = sum_k Xa[c][t][k] * W[c-slice][k][d] + bias ----
// Xa: bf16 [8][16][64] swizzled A-layout.  W row-major, row stride ND, channel stride wCs.
// MODE 0: store bf16 to P[t*1536 + outOff + c*ND + d]
// MODE 1: R[t][i] += val (bf16 RMW; i = c*ND+d, ND==64)
// MODE 2: xca[(tokbase+t)*HD + i] = val (f32) and R[t][i] = bf16(val)
template<int ND, int MODE>
__device__ __forceinline__ void proj_mfma(
    const unsigned char* Xa, unsigned short* P, unsigned short* R,
    const float* __restrict__ W, int wCs,
    const float* __restrict__ bias, int bCs,
    int outOff, float* __restrict__ xca, size_t tokbase,
    int wave, int lane)
{
  const int lr = lane & 15, lg = lane >> 4, lk = lg * 8;
  constexpr int NT = ND / 16, TOT = 8 * NT;
  #pragma unroll 2
  for (int tile = wave; tile < TOT; tile += 4){
    int c = tile / NT, nt = tile - c * NT;
    f32x4 acc = {0.f, 0.f, 0.f, 0.f};
    #pragma unroll
    for (int ks = 0; ks < 2; ks++){
      int k0 = ks * 32 + lk;
      int aaddr = (((c * 16 + lr) * 64 + k0) * 2) ^ SWZ(lr);
      s16x8 af = *(const s16x8*)(Xa + aaddr);
      const float* wp = W + (size_t)c * wCs + (size_t)k0 * ND + nt * 16 + lr;
      s16x8 bfr;
      #pragma unroll
      for (int e = 0; e < 8; e++) bfr[e] = (short)f2bfu(wp[(size_t)e * ND]);
      acc = __builtin_amdgcn_mfma_f32_16x16x32_bf16(af, bfr, acc, 0, 0, 0);
    }
    float bsv = bias[c * bCs + nt * 16 + lr];
    int dcol = c * ND + nt * 16 + lr;
    #pragma unroll
    for (int r = 0; r < 4; r++){
      int t = lg * 4 + r;
      float val = acc[r] + bsv;
      if (MODE == 0){
        P[t * 1536 + outOff + dcol] = f2bfu(val);
      } else if (MODE == 1){
        unsigned short* rp = &R[t * 512 + dcol];
        *rp = f2bfu(bfu2f(*rp) + val);
      } else {
        xca[(tokbase + t) * HD + dcol] = val;
        R[t * 512 + dcol] = f2bfu(val);
      }
    }
  }
}

// ---- criss-cross attention; V=1: qkv in P[t][c*192+{0,64,128}+j]; V=2: q2 [c*64+j], kv [512+c*128+{0,64}+j]
template<int V>
__device__ __forceinline__ void cc_attn(const unsigned short* P, unsigned char* Xa, int tid)
{
  const int t = tid >> 4, j0 = tid & 15;
  const unsigned short* pr = P + t * 1536;
  #pragma unroll
  for (int jj = 0; jj < 4; jj++){
    int j = j0 + jj * 16;
    float qs[8], kk[8], vv[8];
    #pragma unroll
    for (int m = 0; m < 8; m++){
      if (V == 1){
        qs[m] = bfu2f(pr[m * 192 + j]) * 0.125f;
        kk[m] = bfu2f(pr[m * 192 + 64 + j]);
        vv[m] = bfu2f(pr[m * 192 + 128 + j]);
      } else {
        qs[m] = bfu2f(pr[m * 64 + j]) * 0.125f;
        kk[m] = bfu2f(pr[512 + m * 128 + j]);
        vv[m] = bfu2f(pr[512 + m * 128 + 64 + j]);
      }
    }
    float w[8];
    #pragma unroll
    for (int c = 0; c < 8; c++){
      float den = 0.f;
      #pragma unroll
      for (int m = 0; m < 8; m++) den += __expf(qs[c] * kk[m]);
      w[c] = vv[c] / den;
    }
    #pragma unroll
    for (int m = 0; m < 8; m++){
      float o = 0.f;
      #pragma unroll
      for (int c = 0; c < 8; c++) o += w[c] * __expf(qs[c] * kk[m]);
      int addr = (((m * 16 + t) * 64 + j) * 2) ^ SWZ(t);
      *(unsigned short*)(Xa + addr) = f2bfu(o);
    }
  }
}

__global__ __launch_bounds__(256)
void fused_stage_a(const float* __restrict__ x, const float* __restrict__ ctx,
                   const float* __restrict__ ln1w, const float* __restrict__ ln1b,
                   const float* __restrict__ w_qkv, const float* __restrict__ b_qkv,
                   const float* __restrict__ w_fcs, const float* __restrict__ b_fcs,
                   const float* __restrict__ ln2w, const float* __restrict__ ln2b,
                   const float* __restrict__ w_q, const float* __restrict__ b_q,
                   const float* __restrict__ w_kv, const float* __restrict__ b_kv,
                   const float* __restrict__ w_fcc, const float* __restrict__ b_fcc,
                   const float* __restrict__ ln3w, const float* __restrict__ ln3b,
                   float* __restrict__ xca_out, __hip_bfloat16* __restrict__ y_out)
{
  __shared__ __align__(16) unsigned char lds[81920];
  unsigned char*  Xa = lds;                              // [8][16][64] bf16, swizzled (16 KB)
  unsigned short* P  = (unsigned short*)(lds + 16384);   // [16][1536] bf16 (48 KB)
  unsigned short* R  = (unsigned short*)(lds + 65536);   // [16][512]  bf16 (16 KB)

  const int tid = threadIdx.x, lane = tid & 63, wave = tid >> 6;
  const size_t tokbase = (size_t)blockIdx.x * TB;
  const int cXa = lane >> 3, k0Xa = (lane & 7) * 8;      // per-lane Xa write slot

  // ---------- phase 1: LN1(x) -> Xa (bf16) + R (bf16 residual) ----------
  {
    float lw[8], lb[8];
    #pragma unroll
    for (int e = 0; e < 8; e++){ lw[e] = ln1w[lane*8+e]; lb[e] = ln1b[lane*8+e]; }
    for (int tt = 0; tt < 4; tt++){
      int t = wave * 4 + tt;
      const float* xr = x + (tokbase + t) * HD + lane * 8;
      float v[8];
      float4 a0 = *(const float4*)xr, a1 = *(const float4*)(xr + 4);
      v[0]=a0.x; v[1]=a0.y; v[2]=a0.z; v[3]=a0.w; v[4]=a1.x; v[5]=a1.y; v[6]=a1.z; v[7]=a1.w;
      float sm = 0.f, sq = 0.f;
      #pragma unroll
      for (int e = 0; e < 8; e++){ sm += v[e]; sq += v[e]*v[e]; }
      #pragma unroll
      for (int o = 32; o > 0; o >>= 1){ sm += __shfl_xor(sm, o); sq += __shfl_xor(sq, o); }
      float mu = sm * (1.f/512.f), rs = rsqrtf(sq * (1.f/512.f) - mu*mu + 1e-6f);
      float nv[8];
      #pragma unroll
      for (int e = 0; e < 8; e++) nv[e] = (v[e]-mu)*rs*lw[e] + lb[e];
      uint4 pk = pack8(nv);
      *(uint4*)((unsigned char*)R + t*1024 + lane*16) = pk;
      *(uint4*)(Xa + ((((cXa*16 + t)*64 + k0Xa)*2) ^ SWZ(t))) = pk;
    }
  }
  __syncthreads();

  // ---------- phase 2: qkv projection ----------
  proj_mfma<192,0>(Xa, P, R, w_qkv, 64*192, b_qkv, 192, 0, nullptr, tokbase, wave, lane);
  __syncthreads();

  // ---------- phase 3: attention #1 -> Xa ----------
  cc_attn<1>(P, Xa, tid);
  __syncthreads();

  // ---------- phase 4: fc_s, residual into R ----------
  proj_mfma<64,1>(Xa, P, R, w_fcs, 0, b_fcs, 0, 0, nullptr, tokbase, wave, lane);
  __syncthreads();

  // ---------- phase 5: LN2(R) -> Xa (h) ----------
  {
    float lw[8], lb[8];
    #pragma unroll
    for (int e = 0; e < 8; e++){ lw[e] = ln2w[lane*8+e]; lb[e] = ln2b[lane*8+e]; }
    for (int tt = 0; tt < 4; tt++){
      int t = wave * 4 + tt;
      float v[8];
      unpack8(*(const uint4*)((unsigned char*)R + t*1024 + lane*16), v);
      float sm = 0.f, sq = 0.f;
      #pragma unroll
      for (int e = 0; e < 8; e++){ sm += v[e]; sq += v[e]*v[e]; }
      #pragma unroll
      for (int o = 32; o > 0; o >>= 1){ sm += __shfl_xor(sm, o); sq += __shfl_xor(sq, o); }
      float mu = sm * (1.f/512.f), rs = rsqrtf(sq * (1.f/512.f) - mu*mu + 1e-6f);
      float nv[8];
      #pragma unroll
      for (int e = 0; e < 8; e++) nv[e] = (v[e]-mu)*rs*lw[e] + lb[e];
      *(uint4*)(Xa + ((((cXa*16 + t)*64 + k0Xa)*2) ^ SWZ(t))) = pack8(nv);
    }
  }
  __syncthreads();

  // ---------- phase 6: q projection (reads Xa=h) -> P[t][0:512] ----------
  proj_mfma<64,0>(Xa, P, R, w_q, 64*64, b_q, 64, 0, nullptr, tokbase, wave, lane);
  __syncthreads();

  // ---------- phase 7: load context -> Xa ----------
  for (int tt = 0; tt < 4; tt++){
    int t = wave * 4 + tt;
    const float* cr = ctx + (tokbase + t) * HD + lane * 8;
    float v[8];
    float4 a0 = *(const float4*)cr, a1 = *(const float4*)(cr + 4);
    v[0]=a0.x; v[1]=a0.y; v[2]=a0.z; v[3]=a0.w; v[4]=a1.x; v[5]=a1.y; v[6]=a1.z; v[7]=a1.w;
    *(uint4*)(Xa + ((((cXa*16 + t)*64 + k0Xa)*2) ^ SWZ(t))) = pack8(v);
  }
  __syncthreads();

  // ---------- phase 8: kv projection (context) -> P[t][512:1536] ----------
  proj_mfma<128,0>(Xa, P, R, w_kv, 64*128, b_kv, 128, 512, nullptr, tokbase, wave, lane);
  __syncthreads();

  // ---------- phase 9: attention #2 -> Xa ----------
  cc_attn<2>(P, Xa, tid);
  __syncthreads();

  // ---------- phase 10: fc_c -> x_ca (global f32) + R (bf16 for LN3) ----------
  proj_mfma<64,2>(Xa, P, R, w_fcc, 0, b_fcc, 0, 0, xca_out, tokbase, wave, lane);
  __syncthreads();

  // ---------- phase 11: LN3(R) -> y_out (bf16) ----------
  {
    float lw[8], lb[8];
    #pragma unroll
    for (int e = 0; e < 8; e++){ lw[e] = ln3w[lane*8+e]; lb[e] = ln3b[lane*8+e]; }
    for (int tt = 0; tt < 4; tt++){
      int t = wave * 4 + tt;
      float v[8];
      unpack8(*(const uint4*)((unsigned char*)R + t*1024 + lane*16), v);
      float sm = 0.f, sq = 0.f;
      #pragma unroll
      for (int e = 0; e < 8; e++){ sm += v[e]; sq += v[e]*v[e]; }
      #pragma unroll
      for (int o = 32; o > 0; o >>= 1){ sm += __shfl_xor(sm, o); sq += __shfl_xor(sq, o); }
      float mu = sm * (1.f/512.f), rs = rsqrtf(sq * (1.f/512.f) - mu*mu + 1e-6f);
      float nv[8];
      #pragma unroll
      for (int e = 0; e < 8; e++) nv[e] = (v[e]-mu)*rs*lw[e] + lb[e];
      *(uint4*)(y_out + (tokbase + t) * HD + lane * 8) = pack8(nv);
    }
  }
}

// ---------------- MFMA GEMM (unchanged from round 2, verified) ----------------
__device__ __forceinline__ float gelu_exact(float v){
  return 0.5f * v * (1.f + erff(v * 0.70710678118f));
}

template<int EPI>
__global__ __launch_bounds__(256)
void gemm_mfma(const __hip_bfloat16* __restrict__ A, const float* __restrict__ B,
               const float* __restrict__ bias,
               __hip_bfloat16* __restrict__ DstB, float* __restrict__ DstF,
               int M_, int N_, int K_)
{
  __shared__ __align__(16) unsigned short As[128*32];
  __shared__ __align__(16) unsigned short Bs[128*32];

  const int tid  = threadIdx.x;
  const int row0 = blockIdx.x * 128, col0 = blockIdx.y * 128;
  const int lane = tid & 63, wave = tid >> 6;
  const int wr = (wave >> 1) * 64, wc = (wave & 1) * 64;
  const int lr = lane & 15, lk = (lane >> 4) * 8;

  f32x4 acc[4][4];
  #pragma unroll
  for (int i = 0; i < 4; i++)
    #pragma unroll
    for (int j = 0; j < 4; j++)
      #pragma unroll
      for (int r = 0; r < 4; r++) acc[i][j][r] = 0.f;

  for (int k0 = 0; k0 < K_; k0 += 32){
    #pragma unroll
    for (int l = 0; l < 2; l++){
      int off = (l*256 + tid) * 8;
      int r = off >> 5, kc = off & 31;
      uint4 v = *(const uint4*)((const void*)(A + (size_t)(row0 + r)*K_ + k0 + kc));
      *(uint4*)((void*)(As + r*32 + kc)) = v;
    }
    #pragma unroll
    for (int l = 0; l < 2; l++){
      int off = (l*256 + tid) * 8;
      int kr = off >> 7, nc = off & 127;
      const float* bp = B + (size_t)(k0 + kr)*N_ + col0 + nc;
      float4 v0 = *(const float4*)((const void*)bp);
      float4 v1 = *(const float4*)((const void*)(bp + 4));
      float bv[8] = {v0.x, v0.y, v0.z, v0.w, v1.x, v1.y, v1.z, v1.w};
      #pragma unroll
      for (int e = 0; e < 8; e++) Bs[(nc + e)*32 + kr] = f2bfu(bv[e]);
    }
    __syncthreads();

    s16x8 af[4], bfr[4];
    #pragma unroll
    for (int i = 0; i < 4; i++) af[i]  = *(const s16x8*)((const void*)(As + (wr + i*16 + lr)*32 + lk));
    #pragma unroll
    for (int j = 0; j < 4; j++) bfr[j] = *(const s16x8*)((const void*)(Bs + (wc + j*16 + lr)*32 + lk));
    #pragma unroll
    for (int i = 0; i < 4; i++)
      #pragma unroll
      for (int j = 0; j < 4; j++)
        acc[i][j] = __builtin_amdgcn_mfma_f32_16x16x32_bf16(af[i], bfr[j], acc[i][j], 0, 0, 0);
    __syncthreads();
  }

  #pragma unroll
  for (int i = 0; i < 4; i++)
    #pragma unroll
    for (int j = 0; j < 4; j++){
      int col = col0 + wc + j*16 + lr;
      float bc = bias[col];
      #pragma unroll
      for (int r = 0; r < 4; r++){
        int row = row0 + wr + i*16 + (lane >> 4)*4 + r;
        size_t idx = (size_t)row * N_ + col;
        float v = acc[i][j][r] + bc;
        if (EPI == 1) DstB[idx] = f2bf(gelu_exact(v));
        else          DstF[idx] += v;
      }
    }
}

extern "C" void kernel_launch(void* const* d_in, const int* in_sizes, int n_in,
                              void* d_out, int out_size, void* d_ws, size_t ws_size,
                              hipStream_t stream)
{
  const float* x      = (const float*)d_in[0];
  const float* ctx    = (const float*)d_in[1];
  const float* ln1w   = (const float*)d_in[2];
  const float* ln1b   = (const float*)d_in[3];
  const float* w_qkv  = (const float*)d_in[4];
  const float* b_qkv  = (const float*)d_in[5];
  const float* w_fc_s = (const float*)d_in[6];
  const float* b_fc_s = (const float*)d_in[7];
  const float* ln2w   = (const float*)d_in[8];
  const float* ln2b   = (const float*)d_in[9];
  const float* w_q    = (const float*)d_in[10];
  const float* b_q    = (const float*)d_in[11];
  const float* w_kv   = (const float*)d_in[12];
  const float* b_kv   = (const float*)d_in[13];
  const float* w_fc_c = (const float*)d_in[14];
  const float* b_fc_c = (const float*)d_in[15];
  const float* ln3w   = (const float*)d_in[16];
  const float* ln3b   = (const float*)d_in[17];
  const float* w1     = (const float*)d_in[18];
  const float* b1     = (const float*)d_in[19];
  const float* w2     = (const float*)d_in[20];
  const float* b2     = (const float*)d_in[21];

  float* out = (float*)d_out;
  __hip_bfloat16* Y   = (__hip_bfloat16*)d_ws;                                   // 16384x512 bf16
  __hip_bfloat16* mid = (__hip_bfloat16*)((char*)d_ws + (size_t)TOKENS*HD*2);    // 16384x2048 bf16

  fused_stage_a<<<TOKENS/TB, 256, 0, stream>>>(x, ctx, ln1w, ln1b, w_qkv, b_qkv,
                                               w_fc_s, b_fc_s, ln2w, ln2b, w_q, b_q,
                                               w_kv, b_kv, w_fc_c, b_fc_c, ln3w, ln3b,
                                               out, Y);

  gemm_mfma<1><<<dim3(TOKENS/128, MM/128), 256, 0, stream>>>(Y,   w1, b1, mid, nullptr, TOKENS, MM, HD);
  gemm_mfma<2><<<dim3(TOKENS/128, HD/128), 256, 0, stream>>>(mid, w2, b2, nullptr, out, TOKENS, HD, MM);
}

// Round 4
// 236.563 us; speedup vs baseline: 3.5410x; 1.8249x over previous
//
#include <hip/hip_runtime.h>
#include <hip/hip_bf16.h>

#define TOKENS (16*1024)
#define HD 512
#define MM 2048
#define TB 16   // tokens per stage_a block

typedef short s16x8 __attribute__((ext_vector_type(8)));
typedef float f32x4 __attribute__((ext_vector_type(4)));

__device__ __forceinline__ __hip_bfloat16 f2bf(float v){ return __float2bfloat16(v); }
__device__ __forceinline__ float bf2f(__hip_bfloat16 v){ return __bfloat162float(v); }
__device__ __forceinline__ unsigned short f2bfu(float v){
  __hip_bfloat16 b = __float2bfloat16(v);
  unsigned short u; __builtin_memcpy(&u, &b, 2); return u;
}
__device__ __forceinline__ float bfu2f(unsigned short u){
  unsigned int x = ((unsigned int)u) << 16; float f; __builtin_memcpy(&f, &x, 4); return f;
}
__device__ __forceinline__ uint4 pack8(const float* v){
  unsigned short s[8];
  #pragma unroll
  for (int e = 0; e < 8; e++) s[e] = f2bfu(v[e]);
  uint4 u; __builtin_memcpy(&u, s, 16); return u;
}
__device__ __forceinline__ void unpack8(uint4 u, float* v){
  const unsigned short* s = (const unsigned short*)&u;
  #pragma unroll
  for (int e = 0; e < 8; e++) v[e] = bfu2f(s[e]);
}

// async global->LDS, 16B per lane; LDS dest = base + lane*16 (HW), global src per-lane
typedef const __attribute__((address_space(1))) unsigned int* gas_t;
typedef __attribute__((address_space(3))) unsigned int* las_t;
__device__ __forceinline__ void async16(const void* g, void* l){
  __builtin_amdgcn_global_load_lds((gas_t)g, (las_t)l, 16, 0, 0);
}

#define SWZ(t) (((t) & 7) << 4)

// ================= stage_a (unchanged from round 3, verified) =================
template<int ND, int MODE>
__device__ __forceinline__ void proj_mfma(
    const unsigned char* Xa, unsigned short* P, unsigned short* R,
    const float* __restrict__ W, int wCs,
    const float* __restrict__ bias, int bCs,
    int outOff, float* __restrict__ xca, size_t tokbase,
    int wave, int lane)
{
  const int lr = lane & 15, lg = lane >> 4, lk = lg * 8;
  constexpr int NT = ND / 16, TOT = 8 * NT;
  #pragma unroll 2
  for (int tile = wave; tile < TOT; tile += 4){
    int c = tile / NT, nt = tile - c * NT;
    f32x4 acc = {0.f, 0.f, 0.f, 0.f};
    #pragma unroll
    for (int ks = 0; ks < 2; ks++){
      int k0 = ks * 32 + lk;
      int aaddr = (((c * 16 + lr) * 64 + k0) * 2) ^ SWZ(lr);
      s16x8 af = *(const s16x8*)(Xa + aaddr);
      const float* wp = W + (size_t)c * wCs + (size_t)k0 * ND + nt * 16 + lr;
      s16x8 bfr;
      #pragma unroll
      for (int e = 0; e < 8; e++) bfr[e] = (short)f2bfu(wp[(size_t)e * ND]);
      acc = __builtin_amdgcn_mfma_f32_16x16x32_bf16(af, bfr, acc, 0, 0, 0);
    }
    float bsv = bias[c * bCs + nt * 16 + lr];
    int dcol = c * ND + nt * 16 + lr;
    #pragma unroll
    for (int r = 0; r < 4; r++){
      int t = lg * 4 + r;
      float val = acc[r] + bsv;
      if (MODE == 0){
        P[t * 1536 + outOff + dcol] = f2bfu(val);
      } else if (MODE == 1){
        unsigned short* rp = &R[t * 512 + dcol];
        *rp = f2bfu(bfu2f(*rp) + val);
      } else {
        xca[(tokbase + t) * HD + dcol] = val;
        R[t * 512 + dcol] = f2bfu(val);
      }
    }
  }
}

template<int V>
__device__ __forceinline__ void cc_attn(const unsigned short* P, unsigned char* Xa, int tid)
{
  const int t = tid >> 4, j0 = tid & 15;
  const unsigned short* pr = P + t * 1536;
  #pragma unroll
  for (int jj = 0; jj < 4; jj++){
    int j = j0 + jj * 16;
    float qs[8], kk[8], vv[8];
    #pragma unroll
    for (int m = 0; m < 8; m++){
      if (V == 1){
        qs[m] = bfu2f(pr[m * 192 + j]) * 0.125f;
        kk[m] = bfu2f(pr[m * 192 + 64 + j]);
        vv[m] = bfu2f(pr[m * 192 + 128 + j]);
      } else {
        qs[m] = bfu2f(pr[m * 64 + j]) * 0.125f;
        kk[m] = bfu2f(pr[512 + m * 128 + j]);
        vv[m] = bfu2f(pr[512 + m * 128 + 64 + j]);
      }
    }
    float w[8];
    #pragma unroll
    for (int c = 0; c < 8; c++){
      float den = 0.f;
      #pragma unroll
      for (int m = 0; m < 8; m++) den += __expf(qs[c] * kk[m]);
      w[c] = vv[c] / den;
    }
    #pragma unroll
    for (int m = 0; m < 8; m++){
      float o = 0.f;
      #pragma unroll
      for (int c = 0; c < 8; c++) o += w[c] * __expf(qs[c] * kk[m]);
      int addr = (((m * 16 + t) * 64 + j) * 2) ^ SWZ(t);
      *(unsigned short*)(Xa + addr) = f2bfu(o);
    }
  }
}

__global__ __launch_bounds__(256)
void fused_stage_a(const float* __restrict__ x, const float* __restrict__ ctx,
                   const float* __restrict__ ln1w, const float* __restrict__ ln1b,
                   const float* __restrict__ w_qkv, const float* __restrict__ b_qkv,
                   const float* __restrict__ w_fcs, const float* __restrict__ b_fcs,
                   const float* __restrict__ ln2w, const float* __restrict__ ln2b,
                   const float* __restrict__ w_q, const float* __restrict__ b_q,
                   const float* __restrict__ w_kv, const float* __restrict__ b_kv,
                   const float* __restrict__ w_fcc, const float* __restrict__ b_fcc,
                   const float* __restrict__ ln3w, const float* __restrict__ ln3b,
                   float* __restrict__ xca_out, __hip_bfloat16* __restrict__ y_out)
{
  __shared__ __align__(16) unsigned char lds[81920];
  unsigned char*  Xa = lds;                              // [8][16][64] bf16, swizzled (16 KB)
  unsigned short* P  = (unsigned short*)(lds + 16384);   // [16][1536] bf16 (48 KB)
  unsigned short* R  = (unsigned short*)(lds + 65536);   // [16][512]  bf16 (16 KB)

  const int tid = threadIdx.x, lane = tid & 63, wave = tid >> 6;
  const size_t tokbase = (size_t)blockIdx.x * TB;
  const int cXa = lane >> 3, k0Xa = (lane & 7) * 8;

  {
    float lw[8], lb[8];
    #pragma unroll
    for (int e = 0; e < 8; e++){ lw[e] = ln1w[lane*8+e]; lb[e] = ln1b[lane*8+e]; }
    for (int tt = 0; tt < 4; tt++){
      int t = wave * 4 + tt;
      const float* xr = x + (tokbase + t) * HD + lane * 8;
      float v[8];
      float4 a0 = *(const float4*)xr, a1 = *(const float4*)(xr + 4);
      v[0]=a0.x; v[1]=a0.y; v[2]=a0.z; v[3]=a0.w; v[4]=a1.x; v[5]=a1.y; v[6]=a1.z; v[7]=a1.w;
      float sm = 0.f, sq = 0.f;
      #pragma unroll
      for (int e = 0; e < 8; e++){ sm += v[e]; sq += v[e]*v[e]; }
      #pragma unroll
      for (int o = 32; o > 0; o >>= 1){ sm += __shfl_xor(sm, o); sq += __shfl_xor(sq, o); }
      float mu = sm * (1.f/512.f), rs = rsqrtf(sq * (1.f/512.f) - mu*mu + 1e-6f);
      float nv[8];
      #pragma unroll
      for (int e = 0; e < 8; e++) nv[e] = (v[e]-mu)*rs*lw[e] + lb[e];
      uint4 pk = pack8(nv);
      *(uint4*)((unsigned char*)R + t*1024 + lane*16) = pk;
      *(uint4*)(Xa + ((((cXa*16 + t)*64 + k0Xa)*2) ^ SWZ(t))) = pk;
    }
  }
  __syncthreads();

  proj_mfma<192,0>(Xa, P, R, w_qkv, 64*192, b_qkv, 192, 0, nullptr, tokbase, wave, lane);
  __syncthreads();

  cc_attn<1>(P, Xa, tid);
  __syncthreads();

  proj_mfma<64,1>(Xa, P, R, w_fcs, 0, b_fcs, 0, 0, nullptr, tokbase, wave, lane);
  __syncthreads();

  {
    float lw[8], lb[8];
    #pragma unroll
    for (int e = 0; e < 8; e++){ lw[e] = ln2w[lane*8+e]; lb[e] = ln2b[lane*8+e]; }
    for (int tt = 0; tt < 4; tt++){
      int t = wave * 4 + tt;
      float v[8];
      unpack8(*(const uint4*)((unsigned char*)R + t*1024 + lane*16), v);
      float sm = 0.f, sq = 0.f;
      #pragma unroll
      for (int e = 0; e < 8; e++){ sm += v[e]; sq += v[e]*v[e]; }
      #pragma unroll
      for (int o = 32; o > 0; o >>= 1){ sm += __shfl_xor(sm, o); sq += __shfl_xor(sq, o); }
      float mu = sm * (1.f/512.f), rs = rsqrtf(sq * (1.f/512.f) - mu*mu + 1e-6f);
      float nv[8];
      #pragma unroll
      for (int e = 0; e < 8; e++) nv[e] = (v[e]-mu)*rs*lw[e] + lb[e];
      *(uint4*)(Xa + ((((cXa*16 + t)*64 + k0Xa)*2) ^ SWZ(t))) = pack8(nv);
    }
  }
  __syncthreads();

  proj_mfma<64,0>(Xa, P, R, w_q, 64*64, b_q, 64, 0, nullptr, tokbase, wave, lane);
  __syncthreads();

  for (int tt = 0; tt < 4; tt++){
    int t = wave * 4 + tt;
    const float* cr = ctx + (tokbase + t) * HD + lane * 8;
    float v[8];
    float4 a0 = *(const float4*)cr, a1 = *(const float4*)(cr + 4);
    v[0]=a0.x; v[1]=a0.y; v[2]=a0.z; v[3]=a0.w; v[4]=a1.x; v[5]=a1.y; v[6]=a1.z; v[7]=a1.w;
    *(uint4*)(Xa + ((((cXa*16 + t)*64 + k0Xa)*2) ^ SWZ(t))) = pack8(v);
  }
  __syncthreads();

  proj_mfma<128,0>(Xa, P, R, w_kv, 64*128, b_kv, 128, 512, nullptr, tokbase, wave, lane);
  __syncthreads();

  cc_attn<2>(P, Xa, tid);
  __syncthreads();

  proj_mfma<64,2>(Xa, P, R, w_fcc, 0, b_fcc, 0, 0, xca_out, tokbase, wave, lane);
  __syncthreads();

  {
    float lw[8], lb[8];
    #pragma unroll
    for (int e = 0; e < 8; e++){ lw[e] = ln3w[lane*8+e]; lb[e] = ln3b[lane*8+e]; }
    for (int tt = 0; tt < 4; tt++){
      int t = wave * 4 + tt;
      float v[8];
      unpack8(*(const uint4*)((unsigned char*)R + t*1024 + lane*16), v);
      float sm = 0.f, sq = 0.f;
      #pragma unroll
      for (int e = 0; e < 8; e++){ sm += v[e]; sq += v[e]*v[e]; }
      #pragma unroll
      for (int o = 32; o > 0; o >>= 1){ sm += __shfl_xor(sm, o); sq += __shfl_xor(sq, o); }
      float mu = sm * (1.f/512.f), rs = rsqrtf(sq * (1.f/512.f) - mu*mu + 1e-6f);
      float nv[8];
      #pragma unroll
      for (int e = 0; e < 8; e++) nv[e] = (v[e]-mu)*rs*lw[e] + lb[e];
      *(uint4*)(y_out + (tokbase + t) * HD + lane * 8) = pack8(nv);
    }
  }
}

// ================= weight prep: f32 [R][C] -> bf16 [C][R] =================
__global__ __launch_bounds__(256)
void convert_transpose(const float* __restrict__ src, __hip_bfloat16* __restrict__ dst,
                       int R, int C)
{
  __shared__ float tile[32][33];
  const int rb = blockIdx.x * 32, cb = blockIdx.y * 32;
  const int tr = threadIdx.x & 31, tg = threadIdx.x >> 5;
  #pragma unroll
  for (int i = 0; i < 4; i++){
    int r = tg * 4 + i;
    tile[r][tr] = src[(size_t)(rb + r) * C + cb + tr];
  }
  __syncthreads();
  #pragma unroll
  for (int i = 0; i < 4; i++){
    int rr = tg * 4 + i;
    dst[(size_t)(cb + rr) * R + rb + tr] = f2bf(tile[tr][rr]);
  }
}

// ================= MFMA GEMM, m97 structure: A[M][K] bf16, Bt[N][K] bf16 =================
// Staging: global_load_lds width16, linear LDS [row][64k], content swizzled
// (source chunk ^= row&7); fragment reads XOR the same swizzle -> conflict-free.
__device__ __forceinline__ float gelu_exact(float v){
  return 0.5f * v * (1.f + erff(v * 0.70710678118f));
}

template<int EPI>
__global__ __launch_bounds__(256)
void gemm_bt(const __hip_bfloat16* __restrict__ A, const __hip_bfloat16* __restrict__ Bt,
             const float* __restrict__ bias,
             __hip_bfloat16* __restrict__ DstB, float* __restrict__ DstF,
             int M_, int N_, int K_)
{
  __shared__ __align__(16) unsigned char lds[32768];
  unsigned char* As = lds;            // [128][64] bf16, content-swizzled
  unsigned char* Bs = lds + 16384;    // [128][64] bf16 (rows = n), content-swizzled

  const int tid = threadIdx.x, lane = tid & 63, wave = tid >> 6;
  const int row0 = blockIdx.x * 128, col0 = blockIdx.y * 128;
  const int lr = lane & 15, lg = lane >> 4;
  const int wr = (wave >> 1) * 64, wc = (wave & 1) * 64;

  // staging geometry: instr q covers rows wave*32+q*8 .. +8; lane -> row += lane>>3, chunk = lane&7
  const int srow = (lane >> 3), schunk = lane & 7;

  f32x4 acc[4][4];
  #pragma unroll
  for (int i = 0; i < 4; i++)
    #pragma unroll
    for (int j = 0; j < 4; j++)
      acc[i][j] = (f32x4){0.f, 0.f, 0.f, 0.f};

  for (int k0 = 0; k0 < K_; k0 += 64){
    #pragma unroll
    for (int q = 0; q < 4; q++){
      int r  = wave * 32 + q * 8 + srow;
      int ch = schunk ^ (r & 7);
      async16(A  + (size_t)(row0 + r) * K_ + k0 + ch * 8, As + (size_t)(wave*32 + q*8) * 128);
      async16(Bt + (size_t)(col0 + r) * K_ + k0 + ch * 8, Bs + (size_t)(wave*32 + q*8) * 128);
    }
    __syncthreads();   // drains vmcnt(0): tiles resident

    #pragma unroll
    for (int s = 0; s < 2; s++){
      s16x8 af[4], bfr[4];
      #pragma unroll
      for (int i = 0; i < 4; i++){
        int row = wr + i*16 + lr;
        af[i] = *(const s16x8*)(As + row*128 + ((s*64 + lg*16) ^ ((row & 7) << 4)));
      }
      #pragma unroll
      for (int j = 0; j < 4; j++){
        int row = wc + j*16 + lr;
        bfr[j] = *(const s16x8*)(Bs + row*128 + ((s*64 + lg*16) ^ ((row & 7) << 4)));
      }
      #pragma unroll
      for (int i = 0; i < 4; i++)
        #pragma unroll
        for (int j = 0; j < 4; j++)
          acc[i][j] = __builtin_amdgcn_mfma_f32_16x16x32_bf16(af[i], bfr[j], acc[i][j], 0, 0, 0);
    }
    __syncthreads();   // all reads done before next-tile staging
  }

  // epilogue: C/D layout col = lane&15, row-in-16 = (lane>>4)*4 + r
  #pragma unroll
  for (int i = 0; i < 4; i++)
    #pragma unroll
    for (int j = 0; j < 4; j++){
      int col = col0 + wc + j*16 + lr;
      float bc = bias[col];
      #pragma unroll
      for (int r = 0; r < 4; r++){
        int row = row0 + wr + i*16 + lg*4 + r;
        size_t idx = (size_t)row * N_ + col;
        float v = acc[i][j][r] + bc;
        if (EPI == 1) DstB[idx] = f2bf(gelu_exact(v));
        else          DstF[idx] += v;
      }
    }
}

extern "C" void kernel_launch(void* const* d_in, const int* in_sizes, int n_in,
                              void* d_out, int out_size, void* d_ws, size_t ws_size,
                              hipStream_t stream)
{
  const float* x      = (const float*)d_in[0];
  const float* ctx    = (const float*)d_in[1];
  const float* ln1w   = (const float*)d_in[2];
  const float* ln1b   = (const float*)d_in[3];
  const float* w_qkv  = (const float*)d_in[4];
  const float* b_qkv  = (const float*)d_in[5];
  const float* w_fc_s = (const float*)d_in[6];
  const float* b_fc_s = (const float*)d_in[7];
  const float* ln2w   = (const float*)d_in[8];
  const float* ln2b   = (const float*)d_in[9];
  const float* w_q    = (const float*)d_in[10];
  const float* b_q    = (const float*)d_in[11];
  const float* w_kv   = (const float*)d_in[12];
  const float* b_kv   = (const float*)d_in[13];
  const float* w_fc_c = (const float*)d_in[14];
  const float* b_fc_c = (const float*)d_in[15];
  const float* ln3w   = (const float*)d_in[16];
  const float* ln3b   = (const float*)d_in[17];
  const float* w1     = (const float*)d_in[18];
  const float* b1     = (const float*)d_in[19];
  const float* w2     = (const float*)d_in[20];
  const float* b2     = (const float*)d_in[21];

  float* out = (float*)d_out;
  char* wsb = (char*)d_ws;
  __hip_bfloat16* Y   = (__hip_bfloat16*)wsb;                                  // 16 MB
  __hip_bfloat16* mid = (__hip_bfloat16*)(wsb + (size_t)TOKENS*HD*2);          // 64 MB
  __hip_bfloat16* w1t = (__hip_bfloat16*)(wsb + (size_t)TOKENS*HD*2 + (size_t)TOKENS*MM*2);        // [2048][512] 2 MB
  __hip_bfloat16* w2t = (__hip_bfloat16*)(wsb + (size_t)TOKENS*HD*2 + (size_t)TOKENS*MM*2 + (size_t)HD*MM*2); // [512][2048] 2 MB

  convert_transpose<<<dim3(HD/32, MM/32), 256, 0, stream>>>(w1, w1t, HD, MM);  // w1 [512][2048] -> w1t [2048][512]
  convert_transpose<<<dim3(MM/32, HD/32), 256, 0, stream>>>(w2, w2t, MM, HD);  // w2 [2048][512] -> w2t [512][2048]

  fused_stage_a<<<TOKENS/TB, 256, 0, stream>>>(x, ctx, ln1w, ln1b, w_qkv, b_qkv,
                                               w_fc_s, b_fc_s, ln2w, ln2b, w_q, b_q,
                                               w_kv, b_kv, w_fc_c, b_fc_c, ln3w, ln3b,
                                               out, Y);

  gemm_bt<1><<<dim3(TOKENS/128, MM/128), 256, 0, stream>>>(Y,   w1t, b1, mid, nullptr, TOKENS, MM, HD);
  gemm_bt<2><<<dim3(TOKENS/128, HD/128), 256, 0, stream>>>(mid, w2t, b2, nullptr, out, TOKENS, HD, MM);
}